// Round 22
// baseline (66.503 us; speedup 1.0000x reference)
//
#include <hip/hip_runtime.h>
#include <hip/hip_bf16.h>

// Sizes (fixed by the reference)
#define NN 32
#define CC 64
#define TT 300
#define VV 25
#define KK 3
#define OO 64
#define TB 4          // time steps per block
#define SB (TB * VV)  // 100 output spatial positions per block
#define NREP 8        // replicated stats accumulator slots

// ws layout (floats):
//  [0..1024)       NREP*128 replica stats accumulators (sum, sumsq per channel)
//  [1024..7168)    Wpk: 1536 short8 W-fragments (24 KB)
//  [7168..8704)    Apk: 384 short8 A-fragments (6 KB)
//  [16384..)       bf16 y buffer (30.72 MB) if ws_size permits
#define REP_OFF 0
#define WPK_OFF 1024
#define APK_OFF 7168
#define YBF_OFF 16384
#define YBF_BYTES ((size_t)NN * OO * TT * VV * 2)
#define WS_NEED_BF16 ((size_t)YBF_OFF * 4 + YBF_BYTES)

typedef __attribute__((ext_vector_type(8))) short short8;  // 8 bf16 = 4 VGPR
typedef __attribute__((ext_vector_type(4))) float f32x4;

// f32 -> bf16 RNE, integer path (cold code: prep_pack only)
__device__ __forceinline__ unsigned short f2bf(float f) {
    unsigned u = __builtin_bit_cast(unsigned, f);
    u += 0x7FFFu + ((u >> 16) & 1u);
    return (unsigned short)(u >> 16);
}
__device__ __forceinline__ float bf2f(unsigned short b) {
    return __builtin_bit_cast(float, (unsigned)b << 16);
}
// hot path: official paired convert (RNE, x -> low half); compiler emits the
// packed HW convert (m240: hand-written asm was R13's bug). memcpy not
// bit_cast: __hip_bfloat162 is not trivially copyable on this ROCm.
__device__ __forceinline__ unsigned pk2(float a, float b) {
    __hip_bfloat162 h = __float22bfloat162_rn(make_float2(a, b));
    unsigned r;
    __builtin_memcpy(&r, &h, sizeof(r));
    return r;
}

// One-time: zero replica stats, pack W and A into exact MFMA fragment layout.
__global__ __launch_bounds__(512) void prep_pack(const float* __restrict__ A,
                                                 const float* __restrict__ W,
                                                 float* __restrict__ ws) {
    const int i = blockIdx.x * 512 + threadIdx.x;  // grid 4 -> 2048 threads
    if (i < NREP * 128) ws[REP_OFF + i] = 0.0f;
    unsigned short* Wpk = reinterpret_cast<unsigned short*>(ws + WPK_OFF);
    unsigned short* Apk = reinterpret_cast<unsigned short*>(ws + APK_OFF);
    if (i < 1536) {
        // Wpk[mt][kap][lane]: A-operand frag, row o = mt*16+li, k-elems = kap*32+g*8+e
        int mt = i / 384, r = i - mt * 384;
        int kap = r / 64, lane = r - kap * 64;
        int li = lane & 15, g = lane >> 4;
        int o  = mt * 16 + li;
        int k  = kap >> 1, c0 = (kap & 1) * 32 + g * 8;
        const float* wp = W + ((size_t)(k * OO + o)) * CC + c0;
#pragma unroll
        for (int e = 0; e < 8; ++e) Wpk[i * 8 + e] = f2bf(wp[e]);
    } else if (i < 1920) {
        // Apk[k*2+nt][lane]: B-operand frag (A^T), col w = nt*16+li, k-elems v = g*8+e
        // v >= 25 and w >= 25 are ZERO (finite x values * 0 = 0; x side must be
        // finite, never uninitialized-LDS garbage -> R15's NaN failure).
        int j = i - 1536;
        int k = j / 128, r = j - k * 128;
        int nt = r / 64, lane = r - nt * 64;
        int li = lane & 15, g = lane >> 4;
        int w = nt * 16 + li;
#pragma unroll
        for (int e = 0; e < 8; ++e) {
            int v = g * 8 + e;
            float val = (v < VV && w < VV) ? A[(k * VV + v) * VV + w] : 0.0f;
            Apk[j * 8 + e] = f2bf(val);
        }
    }
}

// Block: (n, 4 time steps), 512 threads = 8 waves. R20 kernel with ONE change:
// launch_bounds (512,6) -> (512,8). LDS 38912B fits 4 blocks/CU; natural VGPR
// is 40 (24-reg margin below the 64 cap, unlike R7/R18 whose live sets were
// 70-85 -> spill). Grid back to 2400 (R21's 768-block grid-stride regressed:
// fewer independent blocks = less cross-block phase overlap + worse L2 reuse).
template <int BF16Y>
__global__ __launch_bounds__(512, 8) void gcn_main(const float* __restrict__ x,
                                                   float* __restrict__ ws,
                                                   float* __restrict__ ypre) {
    __shared__ alignas(16) unsigned short xa_s[100 * 192];  // 38400 B (only LDS)
    __shared__ float stats_s[128];

    const int bid  = blockIdx.x;
    const int n    = bid / (TT / TB);
    const int t0   = (bid % (TT / TB)) * TB;
    const int tid  = threadIdx.x;
    const int lane = tid & 63;
    const int wid  = tid >> 6;
    const int li   = lane & 15;   // fragment row/col index
    const int g    = lane >> 4;   // 16-lane group: k-elems = 8g..8g+7

    if (tid < 128) stats_s[tid] = 0.0f;

    // ---- x fragments straight from global: lane (li,g) owns rows (wid+8m)*16+li,
    // elems v = 8g..8g+7 (g=3: only v=24 valid; rest zeroed in-register, finite).
    const float* xn = x + (size_t)n * (CC * TT * VV);
    short8 xf[2];
#pragma unroll
    for (int m = 0; m < 2; ++m) {
        const int row = (wid + 8 * m) * 16 + li;
        const int c = row & 63, t = row >> 6;
        const float* xr = xn + (size_t)c * (TT * VV) + (size_t)(t0 + t) * VV + g * 8;
        float e0, e1, e2, e3, e4, e5, e6, e7;
        if (g < 3) {
            e0 = xr[0]; e1 = xr[1]; e2 = xr[2]; e3 = xr[3];
            e4 = xr[4]; e5 = xr[5]; e6 = xr[6]; e7 = xr[7];
        } else {
            e0 = xr[0];  // v = 24
            e1 = e2 = e3 = e4 = e5 = e6 = e7 = 0.0f;
        }
        unsigned p[4] = {pk2(e0, e1), pk2(e2, e3), pk2(e4, e5), pk2(e6, e7)};
        __builtin_memcpy(&xf[m], p, 16);
    }

    // ---- A^T B-fragments + Phase C W-fragments: 12 coalesced 16B loads, L2-hot.
    const int mtC   = wid >> 1;
    const int halfC = wid & 1;
    short8 afrag[6], wfr[6];
#pragma unroll
    for (int kn = 0; kn < 6; ++kn)
        afrag[kn] = *reinterpret_cast<const short8*>(
            reinterpret_cast<const unsigned short*>(ws + APK_OFF) + ((size_t)kn * 64 + lane) * 8);
#pragma unroll
    for (int kap = 0; kap < 6; ++kap)
        wfr[kap] = *reinterpret_cast<const short8*>(
            reinterpret_cast<const unsigned short*>(ws + WPK_OFF) +
            ((size_t)(mtC * 6 + kap) * 64 + lane) * 8);

    // ---- Phase B: GEMM1 (no pre-barrier: xf is lane-local).
    // M=(t*64+c) 256 rows = 16 Mtiles (2/wave), N=w (2 tiles), K=32.
#pragma unroll
    for (int m = 0; m < 2; ++m) {
        const int mt = wid + 8 * m;
        const int r0 = mt * 16 + g * 4;
        const int tq = r0 >> 6, c0 = r0 & 63;
        const int sa = tq * 25 + li;
        const int w1 = 16 + li;
        const bool w1v = w1 < VV;
        const int sb = tq * 25 + w1;
        unsigned short* p0 = &xa_s[sa * 192 + (c0 ^ ((sa & 7) << 3))];
        unsigned short* p1 = &xa_s[(w1v ? sb : 0) * 192 + (c0 ^ (((w1v ? sb : 0) & 7) << 3))];
#pragma unroll
        for (int k = 0; k < KK; ++k) {
            f32x4 a0 = {0.f,0.f,0.f,0.f}, a1 = {0.f,0.f,0.f,0.f};
            a0 = __builtin_amdgcn_mfma_f32_16x16x32_bf16(xf[m], afrag[k * 2 + 0], a0, 0, 0, 0);
            a1 = __builtin_amdgcn_mfma_f32_16x16x32_bf16(xf[m], afrag[k * 2 + 1], a1, 0, 0, 0);
            uint2 q0 = make_uint2(pk2(a0[0], a0[1]), pk2(a0[2], a0[3]));
            *reinterpret_cast<uint2*>(p0 + k * 64) = q0;
            if (w1v) {
                uint2 q1 = make_uint2(pk2(a1[0], a1[1]), pk2(a1[2], a1[3]));
                *reinterpret_cast<uint2*>(p1 + k * 64) = q1;
            }
        }
    }
    __syncthreads();

    // ---- Phase C: GEMM2. Wave wid owns mt=wid>>1; nt in {0..3} / {4..6}.
    // K=192 = 6 MFMA from wfr (regs) x xa_s. Invalid srow clamps to row 0.
    unsigned short* ybf = reinterpret_cast<unsigned short*>(ws + YBF_OFF);
    const int ttv = TT * VV;
    const int oq  = mtC * 16 + g * 4;   // constant per thread across nt loop
    const int nNt = halfC ? 3 : 4;
    const int ntBase = halfC ? 4 : 0;
    float s1[4] = {0.f,0.f,0.f,0.f}, s2[4] = {0.f,0.f,0.f,0.f};
    for (int qq = 0; qq < nNt; ++qq) {
        const int nt = ntBase + qq;
        const int srow = nt * 16 + li;
        const bool sv = srow < SB;
        const int sr = sv ? srow : 0;
        const unsigned short* xb = &xa_s[sr * 192];
        const int sw = (sr & 7) << 3;
        f32x4 y = {0.f,0.f,0.f,0.f};
#pragma unroll
        for (int kap = 0; kap < 6; ++kap) {
            const short8 xaf = *reinterpret_cast<const short8*>(xb + ((kap * 32 + g * 8) ^ sw));
            y = __builtin_amdgcn_mfma_f32_16x16x32_bf16(wfr[kap], xaf, y, 0, 0, 0);
        }
        const size_t base = ((size_t)n * OO + oq) * ttv + (size_t)t0 * VV + srow;
        float vq[4];
        if (BF16Y) {
            unsigned p01 = pk2(y[0], y[1]);
            unsigned p23 = pk2(y[2], y[3]);
            if (sv) {
                ybf[base          ] = (unsigned short)p01;
                ybf[base +     ttv] = (unsigned short)(p01 >> 16);
                ybf[base + 2 * ttv] = (unsigned short)p23;
                ybf[base + 3 * ttv] = (unsigned short)(p23 >> 16);
            }
            // stats on quantized values (consistent with what bn_relu reads)
            vq[0] = bf2f((unsigned short)p01); vq[1] = bf2f((unsigned short)(p01 >> 16));
            vq[2] = bf2f((unsigned short)p23); vq[3] = bf2f((unsigned short)(p23 >> 16));
        } else {
            if (sv) {
                ypre[base          ] = y[0];
                ypre[base +     ttv] = y[1];
                ypre[base + 2 * ttv] = y[2];
                ypre[base + 3 * ttv] = y[3];
            }
            vq[0] = y[0]; vq[1] = y[1]; vq[2] = y[2]; vq[3] = y[3];
        }
#pragma unroll
        for (int j = 0; j < 4; ++j) {
            float v = sv ? vq[j] : 0.0f;
            s1[j] += v;
            s2[j] += v * v;
        }
    }
    // ---- ONE reduction at kernel end: 4-step shfl over li, LDS atomics, then
    // 128 replicated global atomics. (R14 lesson: per-iter shfl = LDS-pipe flood)
#pragma unroll
    for (int d = 1; d < 16; d <<= 1) {
#pragma unroll
        for (int j = 0; j < 4; ++j) {
            s1[j] += __shfl_xor(s1[j], d);
            s2[j] += __shfl_xor(s2[j], d);
        }
    }
    if (li == 0) {
#pragma unroll
        for (int j = 0; j < 4; ++j) {
            atomicAdd(&stats_s[oq + j], s1[j]);
            atomicAdd(&stats_s[64 + oq + j], s2[j]);
        }
    }
    // NOTE: per-branch bias b.sum(0) is a per-channel constant -> exactly
    // cancelled by training-mode BN. Skipped on purpose (exact).
    __syncthreads();
    if (tid < 128)
        atomicAdd(&ws[REP_OFF + (bid & (NREP - 1)) * 128 + tid], stats_s[tid]);
}

// bn+relu; folds the NREP replica slots inline (wave-uniform, L1-broadcast).
template <int BF16Y>
__global__ __launch_bounds__(256) void bn_relu(float* __restrict__ out,
                                               const float* __restrict__ ws,
                                               const float* __restrict__ gamma,
                                               const float* __restrict__ beta) {
    const int i4 = blockIdx.x * 256 + threadIdx.x;
    const size_t i = (size_t)i4 * 4;
    const int o = (int)((i / (TT * VV)) % OO);  // TT*VV=7500 divisible by 4

    float sum = 0.0f, sq = 0.0f;
#pragma unroll
    for (int r = 0; r < NREP; ++r) {
        sum += ws[REP_OFF + r * 128 + o];
        sq  += ws[REP_OFF + r * 128 + 64 + o];
    }
    const float cnt  = (float)NN * TT * VV;
    const float mean = sum / cnt;
    const float var  = sq / cnt - mean * mean;
    const float inv  = rsqrtf(var + 1e-5f);
    const float sc   = gamma[o] * inv;
    const float sh   = beta[o] - mean * sc;

    float4 v;
    if (BF16Y) {
        const ushort4 u = *reinterpret_cast<const ushort4*>(
            reinterpret_cast<const unsigned short*>(ws + YBF_OFF) + i);
        v.x = bf2f(u.x); v.y = bf2f(u.y); v.z = bf2f(u.z); v.w = bf2f(u.w);
    } else {
        v = *reinterpret_cast<float4*>(out + i);
    }
    v.x = fmaxf(v.x * sc + sh, 0.0f);
    v.y = fmaxf(v.y * sc + sh, 0.0f);
    v.z = fmaxf(v.z * sc + sh, 0.0f);
    v.w = fmaxf(v.w * sc + sh, 0.0f);
    *reinterpret_cast<float4*>(out + i) = v;
}

extern "C" void kernel_launch(void* const* d_in, const int* in_sizes, int n_in,
                              void* d_out, int out_size, void* d_ws, size_t ws_size,
                              hipStream_t stream) {
    const float* x     = (const float*)d_in[0];
    const float* A     = (const float*)d_in[1];
    const float* W     = (const float*)d_in[2];
    // d_in[3] = b : exactly cancelled by training-mode BN, unused
    const float* gamma = (const float*)d_in[4];
    const float* beta  = (const float*)d_in[5];
    float* out = (float*)d_out;
    float* ws  = (float*)d_ws;

    const bool bf16y = ws_size >= WS_NEED_BF16;  // host-side, deterministic

    hipLaunchKernelGGL(prep_pack, dim3(4), dim3(512), 0, stream, A, W, ws);
    if (bf16y) {
        hipLaunchKernelGGL(HIP_KERNEL_NAME(gcn_main<1>), dim3(NN * (TT / TB)), dim3(512),
                           0, stream, x, ws, out);
        hipLaunchKernelGGL(HIP_KERNEL_NAME(bn_relu<1>), dim3((NN * OO * TT * VV) / 4 / 256),
                           dim3(256), 0, stream, out, ws, gamma, beta);
    } else {
        hipLaunchKernelGGL(HIP_KERNEL_NAME(gcn_main<0>), dim3(NN * (TT / TB)), dim3(512),
                           0, stream, x, ws, out);
        hipLaunchKernelGGL(HIP_KERNEL_NAME(bn_relu<0>), dim3((NN * OO * TT * VV) / 4 / 256),
                           dim3(256), 0, stream, out, ws, gamma, beta);
    }
}

// Round 23
// 57.306 us; speedup vs baseline: 1.1605x; 1.1605x over previous
//
#include <hip/hip_runtime.h>
#include <hip/hip_bf16.h>

// Sizes (fixed by the reference)
#define NN 32
#define CC 64
#define TT 300
#define VV 25
#define KK 3
#define OO 64
#define TB 4          // time steps per block
#define SB (TB * VV)  // 100 output spatial positions per block
#define NREP 8        // replicated stats accumulator slots

// ws layout (floats):
//  [0..1024)       NREP*128 replica stats accumulators (sum, sumsq per channel)
//  [1024..7168)    Wpk: 1536 short8 W-fragments (24 KB)
//  [7168..8704)    Apk: 384 short8 A-fragments (6 KB)
//  [16384..)       bf16 y buffer (30.72 MB) if ws_size permits
#define REP_OFF 0
#define WPK_OFF 1024
#define APK_OFF 7168
#define YBF_OFF 16384
#define YBF_BYTES ((size_t)NN * OO * TT * VV * 2)
#define WS_NEED_BF16 ((size_t)YBF_OFF * 4 + YBF_BYTES)

typedef __attribute__((ext_vector_type(8))) short short8;  // 8 bf16 = 4 VGPR
typedef __attribute__((ext_vector_type(4))) float f32x4;

// f32 -> bf16 RNE, integer path (cold code: prep_pack only)
__device__ __forceinline__ unsigned short f2bf(float f) {
    unsigned u = __builtin_bit_cast(unsigned, f);
    u += 0x7FFFu + ((u >> 16) & 1u);
    return (unsigned short)(u >> 16);
}
__device__ __forceinline__ float bf2f(unsigned short b) {
    return __builtin_bit_cast(float, (unsigned)b << 16);
}
// hot path: official paired convert (RNE, x -> low half); compiler emits the
// packed HW convert (m240: hand-written asm was R13's bug). memcpy not
// bit_cast: __hip_bfloat162 is not trivially copyable on this ROCm.
__device__ __forceinline__ unsigned pk2(float a, float b) {
    __hip_bfloat162 h = __float22bfloat162_rn(make_float2(a, b));
    unsigned r;
    __builtin_memcpy(&r, &h, sizeof(r));
    return r;
}

// One-time: zero replica stats, pack W and A into exact MFMA fragment layout.
__global__ __launch_bounds__(512) void prep_pack(const float* __restrict__ A,
                                                 const float* __restrict__ W,
                                                 float* __restrict__ ws) {
    const int i = blockIdx.x * 512 + threadIdx.x;  // grid 4 -> 2048 threads
    if (i < NREP * 128) ws[REP_OFF + i] = 0.0f;
    unsigned short* Wpk = reinterpret_cast<unsigned short*>(ws + WPK_OFF);
    unsigned short* Apk = reinterpret_cast<unsigned short*>(ws + APK_OFF);
    if (i < 1536) {
        // Wpk[mt][kap][lane]: A-operand frag, row o = mt*16+li, k-elems = kap*32+g*8+e
        int mt = i / 384, r = i - mt * 384;
        int kap = r / 64, lane = r - kap * 64;
        int li = lane & 15, g = lane >> 4;
        int o  = mt * 16 + li;
        int k  = kap >> 1, c0 = (kap & 1) * 32 + g * 8;
        const float* wp = W + ((size_t)(k * OO + o)) * CC + c0;
#pragma unroll
        for (int e = 0; e < 8; ++e) Wpk[i * 8 + e] = f2bf(wp[e]);
    } else if (i < 1920) {
        // Apk[k*2+nt][lane]: B-operand frag (A^T), col w = nt*16+li, k-elems v = g*8+e
        // v >= 25 and w >= 25 are ZERO (finite x values * 0 = 0; x side must be
        // finite, never uninitialized-LDS garbage -> R15's NaN failure).
        int j = i - 1536;
        int k = j / 128, r = j - k * 128;
        int nt = r / 64, lane = r - nt * 64;
        int li = lane & 15, g = lane >> 4;
        int w = nt * 16 + li;
#pragma unroll
        for (int e = 0; e < 8; ++e) {
            int v = g * 8 + e;
            float val = (v < VV && w < VV) ? A[(k * VV + v) * VV + w] : 0.0f;
            Apk[j * 8 + e] = f2bf(val);
        }
    }
}

// Block: (n, 4 time steps), 512 threads = 8 waves.  R17 exact (best verified:
// 57.4us total). x fragments direct from global (lane-local, no staging, no
// first barrier); Phase B GEMM1 -> xa_s; barrier; wfr loaded post-barrier
// (compiler rematerializes regardless — R20 A/B showed hoist is neutral);
// Phase C GEMM2 -> bf16 stores + register stats, ONE shfl tree at kernel end.
// Occupancy: (512,6) = 3 blocks/CU. Every attempt at 4 blocks/CU spilled
// (R7/R18/R22 — unified VGPR/AGPR file leaves <64 usable at 8 waves/SIMD).
template <int BF16Y>
__global__ __launch_bounds__(512, 6) void gcn_main(const float* __restrict__ x,
                                                   float* __restrict__ ws,
                                                   float* __restrict__ ypre) {
    __shared__ alignas(16) unsigned short xa_s[100 * 192];  // 38400 B (only LDS)
    __shared__ float stats_s[128];

    const int bid  = blockIdx.x;
    const int n    = bid / (TT / TB);
    const int t0   = (bid % (TT / TB)) * TB;
    const int tid  = threadIdx.x;
    const int lane = tid & 63;
    const int wid  = tid >> 6;
    const int li   = lane & 15;   // fragment row/col index
    const int g    = lane >> 4;   // 16-lane group: k-elems = 8g..8g+7

    if (tid < 128) stats_s[tid] = 0.0f;

    // ---- x fragments straight from global: lane (li,g) owns rows (wid+8m)*16+li,
    // elems v = 8g..8g+7 (g=3: only v=24 valid; rest zeroed in-register, finite).
    const float* xn = x + (size_t)n * (CC * TT * VV);
    short8 xf[2];
#pragma unroll
    for (int m = 0; m < 2; ++m) {
        const int row = (wid + 8 * m) * 16 + li;
        const int c = row & 63, t = row >> 6;
        const float* xr = xn + (size_t)c * (TT * VV) + (size_t)(t0 + t) * VV + g * 8;
        float e0, e1, e2, e3, e4, e5, e6, e7;
        if (g < 3) {
            e0 = xr[0]; e1 = xr[1]; e2 = xr[2]; e3 = xr[3];
            e4 = xr[4]; e5 = xr[5]; e6 = xr[6]; e7 = xr[7];
        } else {
            e0 = xr[0];  // v = 24
            e1 = e2 = e3 = e4 = e5 = e6 = e7 = 0.0f;
        }
        unsigned p[4] = {pk2(e0, e1), pk2(e2, e3), pk2(e4, e5), pk2(e6, e7)};
        __builtin_memcpy(&xf[m], p, 16);
    }

    // ---- A^T B-fragments: 6 coalesced 16B loads (pre-packed, L2-hot)
    short8 afrag[6];
#pragma unroll
    for (int kn = 0; kn < 6; ++kn)
        afrag[kn] = *reinterpret_cast<const short8*>(
            reinterpret_cast<const unsigned short*>(ws + APK_OFF) + ((size_t)kn * 64 + lane) * 8);

    // ---- Phase B: GEMM1 (no pre-barrier: xf is lane-local).
    // M=(t*64+c) 256 rows = 16 Mtiles (2/wave), N=w (2 tiles), K=32.
#pragma unroll
    for (int m = 0; m < 2; ++m) {
        const int mt = wid + 8 * m;
        const int r0 = mt * 16 + g * 4;
        const int tq = r0 >> 6, c0 = r0 & 63;
        const int sa = tq * 25 + li;
        const int w1 = 16 + li;
        const bool w1v = w1 < VV;
        const int sb = tq * 25 + w1;
        unsigned short* p0 = &xa_s[sa * 192 + (c0 ^ ((sa & 7) << 3))];
        unsigned short* p1 = &xa_s[(w1v ? sb : 0) * 192 + (c0 ^ (((w1v ? sb : 0) & 7) << 3))];
#pragma unroll
        for (int k = 0; k < KK; ++k) {
            f32x4 a0 = {0.f,0.f,0.f,0.f}, a1 = {0.f,0.f,0.f,0.f};
            a0 = __builtin_amdgcn_mfma_f32_16x16x32_bf16(xf[m], afrag[k * 2 + 0], a0, 0, 0, 0);
            a1 = __builtin_amdgcn_mfma_f32_16x16x32_bf16(xf[m], afrag[k * 2 + 1], a1, 0, 0, 0);
            uint2 q0 = make_uint2(pk2(a0[0], a0[1]), pk2(a0[2], a0[3]));
            *reinterpret_cast<uint2*>(p0 + k * 64) = q0;
            if (w1v) {
                uint2 q1 = make_uint2(pk2(a1[0], a1[1]), pk2(a1[2], a1[3]));
                *reinterpret_cast<uint2*>(p1 + k * 64) = q1;
            }
        }
    }
    __syncthreads();

    // ---- Phase C's W-fragments (compiler schedules these equivalently whether
    // hoisted or not — R20 A/B was neutral; keep R17's exact form).
    const int mtC   = wid >> 1;
    const int halfC = wid & 1;
    short8 wfr[6];
#pragma unroll
    for (int kap = 0; kap < 6; ++kap)
        wfr[kap] = *reinterpret_cast<const short8*>(
            reinterpret_cast<const unsigned short*>(ws + WPK_OFF) +
            ((size_t)(mtC * 6 + kap) * 64 + lane) * 8);

    // ---- Phase C: GEMM2. Wave wid owns mt=wid>>1; nt in {0..3} / {4..6}.
    // K=192 = 6 MFMA from wfr (regs) x xa_s. Invalid srow clamps to row 0.
    unsigned short* ybf = reinterpret_cast<unsigned short*>(ws + YBF_OFF);
    const int ttv = TT * VV;
    const int oq  = mtC * 16 + g * 4;   // constant per thread across nt loop
    const int nNt = halfC ? 3 : 4;
    const int ntBase = halfC ? 4 : 0;
    float s1[4] = {0.f,0.f,0.f,0.f}, s2[4] = {0.f,0.f,0.f,0.f};
    for (int qq = 0; qq < nNt; ++qq) {
        const int nt = ntBase + qq;
        const int srow = nt * 16 + li;
        const bool sv = srow < SB;
        const int sr = sv ? srow : 0;
        const unsigned short* xb = &xa_s[sr * 192];
        const int sw = (sr & 7) << 3;
        f32x4 y = {0.f,0.f,0.f,0.f};
#pragma unroll
        for (int kap = 0; kap < 6; ++kap) {
            const short8 xaf = *reinterpret_cast<const short8*>(xb + ((kap * 32 + g * 8) ^ sw));
            y = __builtin_amdgcn_mfma_f32_16x16x32_bf16(wfr[kap], xaf, y, 0, 0, 0);
        }
        const size_t base = ((size_t)n * OO + oq) * ttv + (size_t)t0 * VV + srow;
        float vq[4];
        if (BF16Y) {
            unsigned p01 = pk2(y[0], y[1]);
            unsigned p23 = pk2(y[2], y[3]);
            if (sv) {
                ybf[base          ] = (unsigned short)p01;
                ybf[base +     ttv] = (unsigned short)(p01 >> 16);
                ybf[base + 2 * ttv] = (unsigned short)p23;
                ybf[base + 3 * ttv] = (unsigned short)(p23 >> 16);
            }
            // stats on quantized values (consistent with what bn_relu reads)
            vq[0] = bf2f((unsigned short)p01); vq[1] = bf2f((unsigned short)(p01 >> 16));
            vq[2] = bf2f((unsigned short)p23); vq[3] = bf2f((unsigned short)(p23 >> 16));
        } else {
            if (sv) {
                ypre[base          ] = y[0];
                ypre[base +     ttv] = y[1];
                ypre[base + 2 * ttv] = y[2];
                ypre[base + 3 * ttv] = y[3];
            }
            vq[0] = y[0]; vq[1] = y[1]; vq[2] = y[2]; vq[3] = y[3];
        }
#pragma unroll
        for (int j = 0; j < 4; ++j) {
            float v = sv ? vq[j] : 0.0f;
            s1[j] += v;
            s2[j] += v * v;
        }
    }
    // ---- ONE reduction at kernel end: 4-step shfl over li, LDS atomics, then
    // 128 replicated global atomics. (R14 lesson: per-iter shfl = LDS-pipe flood)
#pragma unroll
    for (int d = 1; d < 16; d <<= 1) {
#pragma unroll
        for (int j = 0; j < 4; ++j) {
            s1[j] += __shfl_xor(s1[j], d);
            s2[j] += __shfl_xor(s2[j], d);
        }
    }
    if (li == 0) {
#pragma unroll
        for (int j = 0; j < 4; ++j) {
            atomicAdd(&stats_s[oq + j], s1[j]);
            atomicAdd(&stats_s[64 + oq + j], s2[j]);
        }
    }
    // NOTE: per-branch bias b.sum(0) is a per-channel constant -> exactly
    // cancelled by training-mode BN. Skipped on purpose (exact).
    __syncthreads();
    if (tid < 128)
        atomicAdd(&ws[REP_OFF + (bid & (NREP - 1)) * 128 + tid], stats_s[tid]);
}

// bn+relu; folds the NREP replica slots inline (wave-uniform, L1-broadcast).
template <int BF16Y>
__global__ __launch_bounds__(256) void bn_relu(float* __restrict__ out,
                                               const float* __restrict__ ws,
                                               const float* __restrict__ gamma,
                                               const float* __restrict__ beta) {
    const int i4 = blockIdx.x * 256 + threadIdx.x;
    const size_t i = (size_t)i4 * 4;
    const int o = (int)((i / (TT * VV)) % OO);  // TT*VV=7500 divisible by 4

    float sum = 0.0f, sq = 0.0f;
#pragma unroll
    for (int r = 0; r < NREP; ++r) {
        sum += ws[REP_OFF + r * 128 + o];
        sq  += ws[REP_OFF + r * 128 + 64 + o];
    }
    const float cnt  = (float)NN * TT * VV;
    const float mean = sum / cnt;
    const float var  = sq / cnt - mean * mean;
    const float inv  = rsqrtf(var + 1e-5f);
    const float sc   = gamma[o] * inv;
    const float sh   = beta[o] - mean * sc;

    float4 v;
    if (BF16Y) {
        const ushort4 u = *reinterpret_cast<const ushort4*>(
            reinterpret_cast<const unsigned short*>(ws + YBF_OFF) + i);
        v.x = bf2f(u.x); v.y = bf2f(u.y); v.z = bf2f(u.z); v.w = bf2f(u.w);
    } else {
        v = *reinterpret_cast<float4*>(out + i);
    }
    v.x = fmaxf(v.x * sc + sh, 0.0f);
    v.y = fmaxf(v.y * sc + sh, 0.0f);
    v.z = fmaxf(v.z * sc + sh, 0.0f);
    v.w = fmaxf(v.w * sc + sh, 0.0f);
    *reinterpret_cast<float4*>(out + i) = v;
}

extern "C" void kernel_launch(void* const* d_in, const int* in_sizes, int n_in,
                              void* d_out, int out_size, void* d_ws, size_t ws_size,
                              hipStream_t stream) {
    const float* x     = (const float*)d_in[0];
    const float* A     = (const float*)d_in[1];
    const float* W     = (const float*)d_in[2];
    // d_in[3] = b : exactly cancelled by training-mode BN, unused
    const float* gamma = (const float*)d_in[4];
    const float* beta  = (const float*)d_in[5];
    float* out = (float*)d_out;
    float* ws  = (float*)d_ws;

    const bool bf16y = ws_size >= WS_NEED_BF16;  // host-side, deterministic

    hipLaunchKernelGGL(prep_pack, dim3(4), dim3(512), 0, stream, A, W, ws);
    if (bf16y) {
        hipLaunchKernelGGL(HIP_KERNEL_NAME(gcn_main<1>), dim3(NN * (TT / TB)), dim3(512),
                           0, stream, x, ws, out);
        hipLaunchKernelGGL(HIP_KERNEL_NAME(bn_relu<1>), dim3((NN * OO * TT * VV) / 4 / 256),
                           dim3(256), 0, stream, out, ws, gamma, beta);
    } else {
        hipLaunchKernelGGL(HIP_KERNEL_NAME(gcn_main<0>), dim3(NN * (TT / TB)), dim3(512),
                           0, stream, x, ws, out);
        hipLaunchKernelGGL(HIP_KERNEL_NAME(bn_relu<0>), dim3((NN * OO * TT * VV) / 4 / 256),
                           dim3(256), 0, stream, out, ws, gamma, beta);
    }
}